// Round 6
// baseline (314.647 us; speedup 1.0000x reference)
//
#include <hip/hip_runtime.h>
#include <hip/hip_bf16.h>

typedef unsigned short u16;
typedef unsigned int u32;
typedef long long i64;
typedef __attribute__((ext_vector_type(8))) short bf16x8;
typedef __attribute__((ext_vector_type(4))) float f32x4;

// ---------- bf16 helpers ----------
__device__ __forceinline__ float b2f(u16 u) {
    return __uint_as_float(((u32)u) << 16);
}
__device__ __forceinline__ u16 f2b(float f) {
    u32 u = __float_as_uint(f);
    u32 r = u + 0x7fffu + ((u >> 16) & 1u);   // round-to-nearest-even
    return (u16)(r >> 16);
}
__device__ __forceinline__ void unpk2(uint2 q, float* v) {
    v[0] = __uint_as_float(q.x << 16);
    v[1] = __uint_as_float(q.x & 0xffff0000u);
    v[2] = __uint_as_float(q.y << 16);
    v[3] = __uint_as_float(q.y & 0xffff0000u);
}
__device__ __forceinline__ void load4(const u16* p, float* v) {
    unpk2(*(const uint2*)p, v);
}

// ---------- zero counters + index storage detection (one dispatch) ----------
__global__ __launch_bounds__(256) void zdetect_k(const u32* __restrict__ ei,
                                                 int* __restrict__ flags,
                                                 int* __restrict__ cnt,
                                                 int* __restrict__ cur, int N) {
    int i = blockIdx.x * 256 + threadIdx.x;
    if (i < N) { cnt[i] = 0; cur[i] = 0; }
    if (blockIdx.x == 0 && threadIdx.x < 64) {
        int lane = threadIdx.x;
        int oddZero = 0;
        for (int k = lane; k < 128; k += 64)
            if (ei[2 * k + 1] == 0) oddZero++;
#pragma unroll
        for (int o = 32; o > 0; o >>= 1) oddZero += __shfl_xor(oddZero, o, 64);
        if (lane == 0) flags[0] = (oddZero >= 126) ? 1 : 0;
    }
}

// ---------- normalize indices to int32 + clamp + degree count ----------
__global__ __launch_bounds__(256) void cvtI_k(const void* __restrict__ ein,
                                              const void* __restrict__ rin,
                                              int* __restrict__ ei32,
                                              int* __restrict__ ri32,
                                              int E, const int* __restrict__ flags,
                                              int* __restrict__ cnt, int N, int R) {
    int i = blockIdx.x * 256 + threadIdx.x;
    int f = flags[0];
    if (i < 2 * E) {
        int x = f ? (int)((const i64*)ein)[i] : ((const int*)ein)[i];
        x = max(0, min(x, N - 1));
        ei32[i] = x;
        if (i >= E) atomicAdd(&cnt[x], 1);   // dst half -> in-degree
    }
    if (i < E) {
        int r = f ? (int)((const i64*)rin)[i] : ((const int*)rin)[i];
        ri32[i] = max(0, min(r, R - 1));
    }
}

// ---------- f32 -> bf16 / f32 -> f32 conversion jobs (4 elems/thread) ----------
struct CJob { const float* in; void* out; int n4; int mode; };  // mode 0: ->bf16, 1: copy
struct CJobs { CJob j[9]; };
__global__ __launch_bounds__(256) void cvt_k(CJobs jobs) {
    CJob job = jobs.j[blockIdx.y];
    int i = blockIdx.x * 256 + threadIdx.x;
    if (i < job.n4) {
        float4 v = ((const float4*)job.in)[i];
        if (job.mode == 0) {
            ushort4 w;
            w.x = f2b(v.x); w.y = f2b(v.y); w.z = f2b(v.z); w.w = f2b(v.w);
            ((ushort4*)job.out)[i] = w;
        } else {
            ((float4*)job.out)[i] = v;
        }
    }
}

// ---------- shuffle-based exclusive scan (single block, 1024 thr) ----------
__global__ __launch_bounds__(1024) void scan_k(const int* __restrict__ cnt,
                                               int* __restrict__ rowptr, int n) {
    __shared__ int wsum[16];
    __shared__ int sbase;
    int t = threadIdx.x, wave = t >> 6, lane = t & 63;
    if (t == 0) sbase = 0;
    __syncthreads();
    for (int start = 0; start < n; start += 1024) {
        int i = start + t;
        int v = (i < n) ? cnt[i] : 0;
        int x = v;
#pragma unroll
        for (int o = 1; o < 64; o <<= 1) {
            int y = __shfl_up(x, o, 64);
            if (lane >= o) x += y;
        }
        if (lane == 63) wsum[wave] = x;
        __syncthreads();
        if (wave == 0 && lane < 16) {
            int w = wsum[lane];
            int xw = w;
#pragma unroll
            for (int o = 1; o < 16; o <<= 1) {
                int y = __shfl_up(xw, o, 64);
                if (lane >= o) xw += y;
            }
            wsum[lane] = xw - w;   // exclusive wave offsets
        }
        __syncthreads();
        int base = sbase;
        __syncthreads();
        if (i < n) rowptr[i] = base + wsum[wave] + x - v;
        if (t == 1023) sbase = base + wsum[15] + x;
        __syncthreads();
    }
    if (t == 0) rowptr[n] = sbase;
}

// ---------- scatter edges into CSR, packed (src, rel) ----------
__global__ void scatter_k(const int* __restrict__ src, const int* __restrict__ dst,
                          const int* __restrict__ ridx, const int* __restrict__ rowptr,
                          int* __restrict__ cur, int2* __restrict__ col, int E) {
    int i = blockIdx.x * blockDim.x + threadIdx.x;
    if (i < E) {
        int d = dst[i];
        int pos = rowptr[d] + atomicAdd(&cur[d], 1);
        col[pos] = make_int2(src[i], ridx[i]);
    }
}

// ---------- MFMA GEMM ----------
// blockIdx.y: 0 -> Xin @ {Wl,Wr} -> xl,xr (N rows) ; 1 -> REL @ We -> re (R rows)
__global__ __launch_bounds__(256) void gemm_mfma(
    const u16* __restrict__ Xin, const u16* __restrict__ REL,
    const u16* __restrict__ Wl16, const float* __restrict__ bl,
    const u16* __restrict__ Wr16, const float* __restrict__ br,
    const u16* __restrict__ We16,
    u16* __restrict__ xl, u16* __restrict__ xr,
    u16* __restrict__ re, int N, int R) {
    int wave = threadIdx.x >> 6, lane = threadIdx.x & 63;
    int job = blockIdx.y;
    const u16* in = (job == 0) ? Xin : REL;
    int rows = (job == 0) ? N : R;
    u16* out = (job == 0) ? xl : re;
    int row0 = blockIdx.x * 64 + wave * 16;
    if (row0 >= rows) return;

    int m = lane & 15, quad = lane >> 4;
    size_t row = (size_t)row0 + m;
    bf16x8 a0 = *(const bf16x8*)(in + row * 64 + quad * 8);
    bf16x8 a1 = *(const bf16x8*)(in + row * 64 + 32 + quad * 8);
    const u16* WA = (job == 0) ? Wl16 : We16;

    for (int ct = 0; ct < 16; ct++) {
        int n = ct * 16 + m;
        bf16x8 b0 = *(const bf16x8*)(WA + (size_t)n * 64 + quad * 8);
        bf16x8 b1 = *(const bf16x8*)(WA + (size_t)n * 64 + 32 + quad * 8);
        float bv = (job == 0) ? bl[n] : 0.f;
        f32x4 acc = {bv, bv, bv, bv};
        acc = __builtin_amdgcn_mfma_f32_16x16x32_bf16(a0, b0, acc, 0, 0, 0);
        acc = __builtin_amdgcn_mfma_f32_16x16x32_bf16(a1, b1, acc, 0, 0, 0);
#pragma unroll
        for (int i = 0; i < 4; i++)
            out[(size_t)(row0 + quad * 4 + i) * 256 + n] = f2b(acc[i]);
        if (job == 0) {
            bf16x8 c0 = *(const bf16x8*)(Wr16 + (size_t)n * 64 + quad * 8);
            bf16x8 c1 = *(const bf16x8*)(Wr16 + (size_t)n * 64 + 32 + quad * 8);
            float bv2 = br[n];
            f32x4 acc2 = {bv2, bv2, bv2, bv2};
            acc2 = __builtin_amdgcn_mfma_f32_16x16x32_bf16(a0, c0, acc2, 0, 0, 0);
            acc2 = __builtin_amdgcn_mfma_f32_16x16x32_bf16(a1, c1, acc2, 0, 0, 0);
#pragma unroll
            for (int i = 0; i < 4; i++)
                xr[(size_t)(row0 + quad * 4 + i) * 256 + n] = f2b(acc2[i]);
        }
    }
}

// ---------- fused edge phase: 2-stage software-pipelined gather ----------
// wave per node; lane: head h = lane>>4, channels ci..ci+3, ci = (lane&15)*4.
// Pipeline: cols(g+2) -> rows(g+1) -> compute(g). Static double buffers.
__global__ __launch_bounds__(256) void edge_agg(
    const int* __restrict__ rowptr, const int2* __restrict__ col,
    const u16* __restrict__ xl, const u16* __restrict__ xr,
    const u16* __restrict__ re,
    const float* __restrict__ att, const float* __restrict__ bias,
    u16* __restrict__ outB, float* __restrict__ outF, int writeF32, int N) {
    int node = blockIdx.x * 4 + (threadIdx.x >> 6);
    int lane = threadIdx.x & 63;
    if (node >= N) return;
    int h = lane >> 4;
    int ci = (lane & 15) * 4;
    u32 hoff = (u32)(h * 64 + ci);

    float av[4], xlv[4], xrv[4];
    {
        float4 a4 = *(const float4*)(att + hoff);
        av[0] = a4.x; av[1] = a4.y; av[2] = a4.z; av[3] = a4.w;
    }
    load4(xl + ((u32)node << 8) + hoff, xlv);
    load4(xr + ((u32)node << 8) + hoff, xrv);

    int beg = rowptr[node], end = rowptr[node + 1];
    int deg = end - beg;
    int ngroups = (deg + 3) >> 2;

    float M = -3.0e38f, l = 0.f;
    float acc[4] = {0.f, 0.f, 0.f, 0.f};
    float mea[4] = {0.f, 0.f, 0.f, 0.f};

    int2 C0[4], C1[4];
    uint2 LXa[4], LVa[4], LXb[4], LVb[4];

    auto fetchC = [&](int g, int2* Cb) {
        int base = beg + g * 4;
#pragma unroll
        for (int k = 0; k < 4; k++) {
            int e = base + k;
            Cb[k] = (e < end) ? col[e] : make_int2(0, 0);
        }
    };
    auto fetchR = [&](const int2* Cb, uint2* LXb_, uint2* LVb_) {
#pragma unroll
        for (int k = 0; k < 4; k++) {
            LXb_[k] = *(const uint2*)(xl + ((((u32)Cb[k].x) << 8) + hoff));
            LVb_[k] = *(const uint2*)(re + ((((u32)Cb[k].y) << 8) + hoff));
        }
    };
    auto compute = [&](int g, const uint2 (&LX)[4], const uint2 (&LV)[4]) {
        int base = beg + g * 4;
        float x0[4], x1[4], x2[4], x3[4];
        float t0 = -3.0e38f, t1 = -3.0e38f, t2 = -3.0e38f, t3 = -3.0e38f;
        {
            float v[4];
            unpk2(LX[0], x0); unpk2(LV[0], v);
            if (base + 0 < end) {
                float s = 0.f;
#pragma unroll
                for (int c = 0; c < 4; c++) {
                    mea[c] += v[c];
                    float mm = x0[c] + xrv[c] + v[c];
                    mm = fmaxf(mm, 0.2f * mm);
                    s = fmaf(av[c], mm, s);
                }
                t0 = s;
            }
            unpk2(LX[1], x1); unpk2(LV[1], v);
            if (base + 1 < end) {
                float s = 0.f;
#pragma unroll
                for (int c = 0; c < 4; c++) {
                    mea[c] += v[c];
                    float mm = x1[c] + xrv[c] + v[c];
                    mm = fmaxf(mm, 0.2f * mm);
                    s = fmaf(av[c], mm, s);
                }
                t1 = s;
            }
            unpk2(LX[2], x2); unpk2(LV[2], v);
            if (base + 2 < end) {
                float s = 0.f;
#pragma unroll
                for (int c = 0; c < 4; c++) {
                    mea[c] += v[c];
                    float mm = x2[c] + xrv[c] + v[c];
                    mm = fmaxf(mm, 0.2f * mm);
                    s = fmaf(av[c], mm, s);
                }
                t2 = s;
            }
            unpk2(LX[3], x3); unpk2(LV[3], v);
            if (base + 3 < end) {
                float s = 0.f;
#pragma unroll
                for (int c = 0; c < 4; c++) {
                    mea[c] += v[c];
                    float mm = x3[c] + xrv[c] + v[c];
                    mm = fmaxf(mm, 0.2f * mm);
                    s = fmaf(av[c], mm, s);
                }
                t3 = s;
            }
        }
#pragma unroll
        for (int o = 1; o <= 8; o <<= 1) {
            t0 += __shfl_xor(t0, o, 64);
            t1 += __shfl_xor(t1, o, 64);
            t2 += __shfl_xor(t2, o, 64);
            t3 += __shfl_xor(t3, o, 64);
        }
        float Mn = fmaxf(M, fmaxf(fmaxf(t0, t1), fmaxf(t2, t3)));
        float corr = __expf(M - Mn);
        float p0 = __expf(t0 - Mn), p1 = __expf(t1 - Mn);
        float p2 = __expf(t2 - Mn), p3 = __expf(t3 - Mn);
        l = l * corr + ((p0 + p1) + (p2 + p3));
#pragma unroll
        for (int c = 0; c < 4; c++)
            acc[c] = acc[c] * corr + (p0 * x0[c] + p1 * x1[c]) + (p2 * x2[c] + p3 * x3[c]);
        M = Mn;
    };

    if (ngroups > 0) {
        fetchC(0, C0);
        fetchR(C0, LXa, LVa);
        fetchC(1, C1);
        int g = 0;
        while (true) {
            if (g + 1 < ngroups) fetchR(C1, LXb, LVb);
            fetchC(g + 2, C0);
            compute(g, LXa, LVa);
            g++;
            if (g >= ngroups) break;
            if (g + 1 < ngroups) fetchR(C0, LXa, LVa);
            fetchC(g + 2, C1);
            compute(g, LXb, LVb);
            g++;
            if (g >= ngroups) break;
        }
    }

    // self-loop LAST: m = xl[n] + xr[n] + me[n], me = mean of incoming re rows
    {
        float inv_d = 1.0f / fmaxf((float)deg, 1.0f);
        float ts = 0.f;
#pragma unroll
        for (int c = 0; c < 4; c++) {
            float mm = xlv[c] + xrv[c] + mea[c] * inv_d;
            mm = fmaxf(mm, 0.2f * mm);
            ts = fmaf(av[c], mm, ts);
        }
#pragma unroll
        for (int o = 1; o <= 8; o <<= 1) ts += __shfl_xor(ts, o, 64);
        float Mn = fmaxf(M, ts);
        float corr = __expf(M - Mn);
        float ps = __expf(ts - Mn);
        l = l * corr + ps;
#pragma unroll
        for (int c = 0; c < 4; c++) acc[c] = acc[c] * corr + ps * xlv[c];
    }

    float o4[4];
    float invl = 1.0f / l;
#pragma unroll
    for (int c = 0; c < 4; c++) o4[c] = acc[c] * invl;
#pragma unroll
    for (int c = 0; c < 4; c++) {
        o4[c] += __shfl_xor(o4[c], 16, 64);
        o4[c] += __shfl_xor(o4[c], 32, 64);
    }
    if (lane < 16) {
        float4 b4 = *(const float4*)(bias + ci);
        float r0 = o4[0] * 0.25f + b4.x;
        float r1 = o4[1] * 0.25f + b4.y;
        float r2 = o4[2] * 0.25f + b4.z;
        float r3 = o4[3] * 0.25f + b4.w;
        if (writeF32) {
            float4 w = {r0, r1, r2, r3};
            *(float4*)(outF + (size_t)node * 64 + ci) = w;
        } else {
            ushort4 w;
            w.x = f2b(r0); w.y = f2b(r1); w.z = f2b(r2); w.w = f2b(r3);
            *(ushort4*)(outB + (size_t)node * 64 + ci) = w;
        }
    }
}

// ---------- launch ----------
extern "C" void kernel_launch(void* const* d_in, const int* in_sizes, int n_in,
                              void* d_out, int out_size, void* d_ws, size_t ws_size,
                              hipStream_t stream) {
    const float* xf   = (const float*)d_in[0];
    const float* relf = (const float*)d_in[2];

    const int N = in_sizes[0] / 64;   // 20000
    const int E = in_sizes[3];        // 320000
    const int R = in_sizes[2] / 64;   // 512

    const float* Wl[2] = {(const float*)d_in[4],  (const float*)d_in[11]};
    const float* bl[2] = {(const float*)d_in[5],  (const float*)d_in[12]};
    const float* Wr[2] = {(const float*)d_in[6],  (const float*)d_in[13]};
    const float* br[2] = {(const float*)d_in[7],  (const float*)d_in[14]};
    const float* We[2] = {(const float*)d_in[8],  (const float*)d_in[15]};
    const float* at[2] = {(const float*)d_in[9],  (const float*)d_in[16]};
    const float* bb[2] = {(const float*)d_in[10], (const float*)d_in[17]};

    // workspace carve
    char* p = (char*)d_ws;
    auto alloc = [&](size_t bytes) -> void* {
        void* r = (void*)p;
        p += (bytes + 255) & ~(size_t)255;
        return r;
    };
    int* flags   = (int*)alloc(256);
    int* ei32    = (int*)alloc((size_t)2 * E * 4);
    int* ri32    = (int*)alloc((size_t)E * 4);
    u16* x16     = (u16*)alloc((size_t)N * 64 * 2);
    u16* rel16   = (u16*)alloc((size_t)R * 64 * 2);
    u16* w16[6];
    for (int i = 0; i < 6; i++) w16[i] = (u16*)alloc((size_t)256 * 64 * 2);
    int* cnt     = (int*)alloc((size_t)N * 4);
    int* cur     = (int*)alloc((size_t)N * 4);
    int* rowptr  = (int*)alloc((size_t)(N + 1) * 4);
    int2* col    = (int2*)alloc((size_t)E * 8);
    u16* xlb = (u16*)alloc((size_t)N * 256 * 2);
    u16* xrb = (u16*)alloc((size_t)N * 256 * 2);
    u16* reb = (u16*)alloc((size_t)R * 256 * 2);
    u16* h0  = (u16*)alloc((size_t)N * 64 * 2);

    float* out = (float*)d_out;

    // 1. zero counters + detect index storage
    zdetect_k<<<(N + 255) / 256, 256, 0, stream>>>((const u32*)d_in[1], flags,
                                                   cnt, cur, N);
    // 2. normalize + clamp indices, count in-degrees
    cvtI_k<<<(2 * E + 255) / 256, 256, 0, stream>>>(d_in[1], d_in[3], ei32, ri32,
                                                    E, flags, cnt, N, R);
    const int* src = ei32;
    const int* dst = ei32 + E;

    // 3. conversions: x, relations, 6 weights -> bf16; relations -> out (f32 copy)
    CJobs jobs;
    jobs.j[0] = {xf,    x16,    N * 16,   0};
    jobs.j[1] = {relf,  rel16,  R * 16,   0};
    jobs.j[2] = {Wl[0], w16[0], 256 * 16, 0};
    jobs.j[3] = {Wr[0], w16[1], 256 * 16, 0};
    jobs.j[4] = {We[0], w16[2], 256 * 16, 0};
    jobs.j[5] = {Wl[1], w16[3], 256 * 16, 0};
    jobs.j[6] = {Wr[1], w16[4], 256 * 16, 0};
    jobs.j[7] = {We[1], w16[5], 256 * 16, 0};
    jobs.j[8] = {relf,  out + (size_t)N * 64, R * 16, 1};
    dim3 cgrid((N * 16 + 255) / 256, 9);
    cvt_k<<<cgrid, 256, 0, stream>>>(jobs);

    // 4. CSR build
    scan_k<<<1, 1024, 0, stream>>>(cnt, rowptr, N);
    scatter_k<<<(E + 255) / 256, 256, 0, stream>>>(src, dst, ri32, rowptr, cur,
                                                   col, E);

    // 5. two GATv2 layers
    dim3 ggrid((N + 63) / 64, 2);
    for (int L = 0; L < 2; L++) {
        const u16* xin = (L == 0) ? x16 : h0;
        gemm_mfma<<<ggrid, 256, 0, stream>>>(xin, rel16,
                                             w16[L * 3 + 0], bl[L],
                                             w16[L * 3 + 1], br[L],
                                             w16[L * 3 + 2],
                                             xlb, xrb, reb, N, R);
        edge_agg<<<(N + 3) / 4, 256, 0, stream>>>(rowptr, col,
                                                  xlb, xrb, reb,
                                                  at[L], bb[L],
                                                  h0, out, (L == 1) ? 1 : 0, N);
    }
}